// Round 1
// baseline (368.248 us; speedup 1.0000x reference)
//
#include <hip/hip_runtime.h>

#define GROUPS 32
#define CCH 256      // channels (Cy == Cx == 256)
#define EE 32        // embed dim
#define HS 64        // low-res H
#define WSZ 64       // low-res W
#define BB 4
#define EPSV 1e-5f

// ---------------- GroupNorm stats: one block per (b, group) ----------------
__global__ __launch_bounds__(256) void gn_stats_kernel(const float* __restrict__ src,
                                                       float* __restrict__ stats,
                                                       int nelem) {
    int grp = blockIdx.x;
    const float4* p = (const float4*)(src + (size_t)grp * nelem);
    int n4 = nelem >> 2;
    float s = 0.f, ss = 0.f;
    for (int i = threadIdx.x; i < n4; i += 256) {
        float4 v = p[i];
        s  += v.x + v.y + v.z + v.w;
        ss += v.x*v.x + v.y*v.y + v.z*v.z + v.w*v.w;
    }
    for (int off = 32; off > 0; off >>= 1) {
        s  += __shfl_down(s, off);
        ss += __shfl_down(ss, off);
    }
    __shared__ float red[8];
    int wid = threadIdx.x >> 6;
    int lane = threadIdx.x & 63;
    if (lane == 0) { red[wid*2] = s; red[wid*2+1] = ss; }
    __syncthreads();
    if (threadIdx.x == 0) {
        float ts = 0.f, tss = 0.f;
        for (int w = 0; w < 4; ++w) { ts += red[w*2]; tss += red[w*2+1]; }
        float mu  = ts / (float)nelem;
        float var = tss / (float)nelem - mu*mu;
        stats[grp*2+0] = mu;
        stats[grp*2+1] = rsqrtf(var + EPSV);
    }
}

// ------- Fold GN affine + stats into projection weights, per batch ---------
// WeffT layout: [B][C][E] (c-major so per-c the 32 weights are contiguous)
__global__ __launch_bounds__(64) void make_eff_kernel(const float* __restrict__ w,     // [E][C]
                                                      const float* __restrict__ bias,  // [E]
                                                      const float* __restrict__ gamma, // [C]
                                                      const float* __restrict__ beta,  // [C]
                                                      const float* __restrict__ stats, // [B*GROUPS][2]
                                                      float* __restrict__ WeffT,       // [B][C][E]
                                                      float* __restrict__ beff)        // [B][E]
{
    int b = blockIdx.x >> 5;
    int e = blockIdx.x & 31;
    float partial = 0.f;
    for (int c = threadIdx.x; c < CCH; c += 64) {
        int g = c >> 3;   // C/GROUPS = 8 channels per group
        float mu = stats[(b*GROUPS + g)*2 + 0];
        float rs = stats[(b*GROUPS + g)*2 + 1];
        float wc = w[e*CCH + c];
        float ga = gamma[c];
        float be = beta[c];
        float weff = wc * ga * rs;
        WeffT[((size_t)b*CCH + c)*EE + e] = weff;
        partial += wc * be - weff * mu;
    }
    for (int off = 32; off > 0; off >>= 1) partial += __shfl_down(partial, off);
    if (threadIdx.x == 0) beff[b*EE + e] = partial + bias[e];
}

// ---------------- 1x1 projection: dst[b][pix][e] = Weff . src ---------------
// Block: 256 threads = 64 pixel-groups (2 px each) x 4 e-groups (8 e each).
// Block covers 128 pixels, all 32 e.
__global__ __launch_bounds__(256) void proj_kernel(const float* __restrict__ src,    // [B][C][npix]
                                                   const float* __restrict__ WeffT,  // [B][C][E]
                                                   const float* __restrict__ beff,   // [B][E]
                                                   float* __restrict__ dst,          // [B][npix][E]
                                                   int npix)
{
    __shared__ float4 sW[CCH*8];   // [c][e/4], 32 KB
    int b = blockIdx.y;
    int pix0 = blockIdx.x * 128;
    const float4* wsrc = (const float4*)(WeffT + (size_t)b*CCH*EE);
    for (int i = threadIdx.x; i < CCH*8; i += 256) sW[i] = wsrc[i];
    int pg = threadIdx.x & 63;
    int eg = threadIdx.x >> 6;
    float acc[2][8];
    #pragma unroll
    for (int j = 0; j < 8; ++j) {
        float bvj = beff[b*EE + eg*8 + j];
        acc[0][j] = bvj; acc[1][j] = bvj;
    }
    __syncthreads();
    const float* ysrc = src + (size_t)b*CCH*npix + pix0 + pg*2;
    #pragma unroll 4
    for (int c = 0; c < CCH; ++c) {
        float2 yv = *(const float2*)(ysrc + (size_t)c*npix);
        float4 wa = sW[c*8 + eg*2 + 0];
        float4 wb = sW[c*8 + eg*2 + 1];
        acc[0][0] = fmaf(yv.x, wa.x, acc[0][0]);
        acc[0][1] = fmaf(yv.x, wa.y, acc[0][1]);
        acc[0][2] = fmaf(yv.x, wa.z, acc[0][2]);
        acc[0][3] = fmaf(yv.x, wa.w, acc[0][3]);
        acc[0][4] = fmaf(yv.x, wb.x, acc[0][4]);
        acc[0][5] = fmaf(yv.x, wb.y, acc[0][5]);
        acc[0][6] = fmaf(yv.x, wb.z, acc[0][6]);
        acc[0][7] = fmaf(yv.x, wb.w, acc[0][7]);
        acc[1][0] = fmaf(yv.y, wa.x, acc[1][0]);
        acc[1][1] = fmaf(yv.y, wa.y, acc[1][1]);
        acc[1][2] = fmaf(yv.y, wa.z, acc[1][2]);
        acc[1][3] = fmaf(yv.y, wa.w, acc[1][3]);
        acc[1][4] = fmaf(yv.y, wb.x, acc[1][4]);
        acc[1][5] = fmaf(yv.y, wb.y, acc[1][5]);
        acc[1][6] = fmaf(yv.y, wb.z, acc[1][6]);
        acc[1][7] = fmaf(yv.y, wb.w, acc[1][7]);
    }
    float* dbase = dst + ((size_t)b*npix + pix0 + pg*2)*EE + eg*8;
    #pragma unroll
    for (int px = 0; px < 2; ++px) {
        float4 o0 = {acc[px][0], acc[px][1], acc[px][2], acc[px][3]};
        float4 o1 = {acc[px][4], acc[px][5], acc[px][6], acc[px][7]};
        *(float4*)(dbase + px*EE + 0) = o0;
        *(float4*)(dbase + px*EE + 4) = o1;
    }
}

// ---------------- Attention + weighted gather ----------------
// Block: 256 threads, tile = one low-res row segment of 16 pixels (= 64 hi-res px).
// tid -> p = tid&63 (hi-res pixel), ci = tid>>6 (wave id; channel quadrant).
#define TW 16
__global__ __launch_bounds__(256) void attn_kernel(const float* __restrict__ q,   // [B][16384][32]
                                                   const float* __restrict__ kk,  // [B][4096][32]
                                                   const float* __restrict__ x,   // [B][C][64][64]
                                                   float* __restrict__ out)       // [B][C][128][128]
{
    __shared__ float sK[5][20][36];   // halo k-vectors, padded stride 36 (bank-safe)
    __shared__ float sLog[64][26];    // raw logits
    __shared__ float sX[16][5][20];   // x tile, 16 channels at a time
    int w0 = blockIdx.x * TW;
    int h  = blockIdx.y;
    int b  = blockIdx.z;
    int tid = threadIdx.x;

    // Phase 1: stage k halo (5 rows x 20 cols x 32e), zero-padded
    for (int i = tid; i < 5*20*32; i += 256) {
        int e  = i & 31;
        int cv = i >> 5;
        int r  = cv / 20;
        int cl = cv - 20*r;
        int gh = h + r - 2;
        int gw = w0 + cl - 2;
        float val = 0.f;
        if (gh >= 0 && gh < HS && gw >= 0 && gw < WSZ)
            val = kk[((size_t)b*4096 + gh*WSZ + gw)*EE + e];
        sK[r][cl][e] = val;
    }

    int p  = tid & 63;
    int ci = tid >> 6;
    int wl = p >> 2;
    int u  = (p >> 1) & 1;
    int v  = p & 1;
    int hh = 2*h + u;
    int ww = 2*(w0 + wl) + v;

    // load this pixel's q vector (redundant across the 4 waves; L1 absorbs)
    float qv[32];
    {
        const float4* qp = (const float4*)(q + ((size_t)b*16384 + hh*128 + ww)*EE);
        #pragma unroll
        for (int i4 = 0; i4 < 8; ++i4) {
            float4 t = qp[i4];
            qv[i4*4+0] = t.x; qv[i4*4+1] = t.y; qv[i4*4+2] = t.z; qv[i4*4+3] = t.w;
        }
    }
    __syncthreads();

    // Phase 2a: each wave computes a subset of the 25 logits (7/6/6/6)
    int jlo = (ci == 0) ? 0 : (6*ci + 1);
    int jhi = 6*(ci+1) + 1;
    if (jhi > 25) jhi = 25;
    for (int j = jlo; j < jhi; ++j) {
        int dy = j / 5;
        int dx = j - 5*dy;
        const float* kp = &sK[dy][wl+dx][0];
        float acc = 0.f;
        #pragma unroll
        for (int e = 0; e < 32; ++e) acc = fmaf(qv[e], kp[e], acc);
        sLog[p][j] = acc;
    }
    __syncthreads();

    // Phase 2b: softmax over 25, redundantly per thread -> attn in registers
    float a[25];
    float m = -1e30f;
    #pragma unroll
    for (int j = 0; j < 25; ++j) { a[j] = sLog[p][j]; m = fmaxf(m, a[j]); }
    float s = 0.f;
    #pragma unroll
    for (int j = 0; j < 25; ++j) { a[j] = __expf(a[j] - m); s += a[j]; }
    float inv = 1.f / s;
    #pragma unroll
    for (int j = 0; j < 25; ++j) a[j] *= inv;

    // Phase 3: weighted gather over 256 channels, 16 at a time
    for (int c0 = 0; c0 < CCH; c0 += 16) {
        __syncthreads();
        for (int i = tid; i < 16*100; i += 256) {
            int cc = i / 100;
            int rc = i - 100*cc;
            int r  = rc / 20;
            int cl = rc - 20*r;
            int gh = h + r - 2;
            int gw = w0 + cl - 2;
            float val = 0.f;
            if (gh >= 0 && gh < HS && gw >= 0 && gw < WSZ)
                val = x[((size_t)(b*CCH + c0 + cc)*HS + gh)*WSZ + gw];
            sX[cc][r][cl] = val;
        }
        __syncthreads();
        #pragma unroll
        for (int t = 0; t < 4; ++t) {
            int cc = ci*4 + t;   // wave-uniform channel
            float acc = 0.f;
            #pragma unroll
            for (int dy = 0; dy < 5; ++dy) {
                const float* xr = &sX[cc][dy][wl];
                #pragma unroll
                for (int dx = 0; dx < 5; ++dx)
                    acc = fmaf(a[dy*5+dx], xr[dx], acc);
            }
            out[((size_t)(b*CCH + c0 + cc)*128 + hh)*128 + ww] = acc;
        }
    }
}

extern "C" void kernel_launch(void* const* d_in, const int* in_sizes, int n_in,
                              void* d_out, int out_size, void* d_ws, size_t ws_size,
                              hipStream_t stream) {
    const float* y   = (const float*)d_in[0];
    const float* x   = (const float*)d_in[1];
    const float* gyw = (const float*)d_in[2];
    const float* gyb = (const float*)d_in[3];
    const float* gxw = (const float*)d_in[4];
    const float* gxb = (const float*)d_in[5];
    const float* qw  = (const float*)d_in[6];
    const float* qb  = (const float*)d_in[7];
    const float* kw  = (const float*)d_in[8];
    const float* kb  = (const float*)d_in[9];
    float* out = (float*)d_out;
    float* ws  = (float*)d_ws;

    float* stats_y = ws;            // 256
    float* stats_x = ws + 256;      // 256
    float* WeffQ   = ws + 512;      // 32768
    float* beffQ   = ws + 33280;    // 128
    float* WeffK   = ws + 33408;    // 32768
    float* beffK   = ws + 66176;    // 128
    float* qbuf    = ws + 66304;    // 4*16384*32 = 2097152
    float* kbuf    = ws + 2163456;  // 4*4096*32  = 524288

    gn_stats_kernel<<<128, 256, 0, stream>>>(y, stats_y, 8*128*128);
    gn_stats_kernel<<<128, 256, 0, stream>>>(x, stats_x, 8*64*64);
    make_eff_kernel<<<128, 64, 0, stream>>>(qw, qb, gyw, gyb, stats_y, WeffQ, beffQ);
    make_eff_kernel<<<128, 64, 0, stream>>>(kw, kb, gxw, gxb, stats_x, WeffK, beffK);
    proj_kernel<<<dim3(128, 4), 256, 0, stream>>>(y, WeffQ, beffQ, qbuf, 16384);
    proj_kernel<<<dim3(32, 4),  256, 0, stream>>>(x, WeffK, beffK, kbuf, 4096);
    attn_kernel<<<dim3(4, 64, 4), 256, 0, stream>>>(qbuf, kbuf, x, out);
}

// Round 3
// 309.199 us; speedup vs baseline: 1.1910x; 1.1910x over previous
//
#include <hip/hip_runtime.h>

#define EPSV 1e-5f

// ---------------- zero the stats accumulators ----------------
__global__ __launch_bounds__(256) void zero_kernel(float* __restrict__ p, int n) {
    int i = blockIdx.x * 256 + threadIdx.x;
    if (i < n) p[i] = 0.f;
}

// ------- stage-1 GroupNorm stats: each block reduces 16384 contiguous floats -------
__global__ __launch_bounds__(256) void stats_partial_kernel(const float* __restrict__ src,
                                                            float* __restrict__ acc,
                                                            int log2_bpg) {
    int grp = blockIdx.x >> log2_bpg;
    const float4* p = (const float4*)(src + (size_t)blockIdx.x * 16384);
    float s = 0.f, ss = 0.f;
    #pragma unroll 4
    for (int i = threadIdx.x; i < 4096; i += 256) {
        float4 v = p[i];
        s  += v.x + v.y + v.z + v.w;
        ss += v.x*v.x + v.y*v.y + v.z*v.z + v.w*v.w;
    }
    for (int off = 32; off > 0; off >>= 1) {
        s  += __shfl_down(s, off);
        ss += __shfl_down(ss, off);
    }
    __shared__ float red[8];
    int wid = threadIdx.x >> 6, lane = threadIdx.x & 63;
    if (lane == 0) { red[wid*2] = s; red[wid*2+1] = ss; }
    __syncthreads();
    if (threadIdx.x == 0) {
        float ts  = red[0] + red[2] + red[4] + red[6];
        float tss = red[1] + red[3] + red[5] + red[7];
        atomicAdd(&acc[grp*2+0], ts);
        atomicAdd(&acc[grp*2+1], tss);
    }
}

// ------- fold GN affine + stats into projection weights, per batch ---------
__global__ __launch_bounds__(64) void make_eff_kernel(const float* __restrict__ w,     // [E][C]
                                                      const float* __restrict__ bias,  // [E]
                                                      const float* __restrict__ gamma, // [C]
                                                      const float* __restrict__ beta,  // [C]
                                                      const float* __restrict__ sums,  // [B*32][2]
                                                      float inv_n,
                                                      float* __restrict__ WeffT,       // [B][C][E]
                                                      float* __restrict__ beff)        // [B][E]
{
    int b = blockIdx.x >> 5;
    int e = blockIdx.x & 31;
    float partial = 0.f;
    for (int c = threadIdx.x; c < 256; c += 64) {
        int g = c >> 3;   // 8 channels per group
        float s  = sums[(b*32 + g)*2 + 0];
        float ss = sums[(b*32 + g)*2 + 1];
        float mu = s * inv_n;
        float rs = rsqrtf(fmaf(-mu, mu, ss * inv_n) + EPSV);
        float wc = w[e*256 + c];
        float weff = wc * gamma[c] * rs;
        WeffT[((size_t)b*256 + c)*32 + e] = weff;
        partial += wc * beta[c] - weff * mu;
    }
    for (int off = 32; off > 0; off >>= 1) partial += __shfl_down(partial, off);
    if (threadIdx.x == 0) beff[b*32 + e] = partial + bias[e];
}

// ---------------- 1x1 projection: dst[b][pix][e] = Weff . src ---------------
// 256 threads = 64 pixel-groups (PPT px each) x 4 e-groups (8 e each).
// Weights are wave-uniform -> scalar (s_load) path.
template<int PPT>
__global__ __launch_bounds__(256) void proj_kernel(const float* __restrict__ src,    // [B][C][npix]
                                                   const float* __restrict__ WeffT,  // [B][C][E]
                                                   const float* __restrict__ beff,   // [B][E]
                                                   float* __restrict__ dst,          // [B][npix][E]
                                                   int npix)
{
    int b = blockIdx.y;
    int pix0 = blockIdx.x * (64*PPT) + (threadIdx.x & 63) * PPT;
    int eg = __builtin_amdgcn_readfirstlane(threadIdx.x >> 6);   // wave-uniform
    const float* wp = WeffT + (size_t)b*256*32 + eg*8;           // uniform base
    float acc[PPT][8];
    #pragma unroll
    for (int j = 0; j < 8; ++j) {
        float bv = beff[b*32 + eg*8 + j];
        #pragma unroll
        for (int px = 0; px < PPT; ++px) acc[px][j] = bv;
    }
    const float* ysrc = src + (size_t)b*256*npix + pix0;
    #pragma unroll 4
    for (int c = 0; c < 256; ++c) {
        float yv[PPT];
        if constexpr (PPT == 4) {
            float4 t = *(const float4*)(ysrc + (size_t)c*npix);
            yv[0]=t.x; yv[1]=t.y; yv[2]=t.z; yv[3]=t.w;
        } else {
            float2 t = *(const float2*)(ysrc + (size_t)c*npix);
            yv[0]=t.x; yv[1]=t.y;
        }
        #pragma unroll
        for (int j = 0; j < 8; ++j) {
            float wj = wp[c*32 + j];    // scalar load (wave-uniform)
            #pragma unroll
            for (int px = 0; px < PPT; ++px)
                acc[px][j] = fmaf(yv[px], wj, acc[px][j]);
        }
    }
    float* dbase = dst + ((size_t)b*npix + pix0)*32 + eg*8;
    #pragma unroll
    for (int px = 0; px < PPT; ++px) {
        float4 o0 = {acc[px][0], acc[px][1], acc[px][2], acc[px][3]};
        float4 o1 = {acc[px][4], acc[px][5], acc[px][6], acc[px][7]};
        *(float4*)(dbase + px*32 + 0) = o0;
        *(float4*)(dbase + px*32 + 4) = o1;
    }
}

// ---------------- attention + gather ----------------
// Block = 8x8 low-res tile, 256 threads, channel-split x2 (128 ch per block).
// sA swizzle: base = child*27 + (child>>5)*4.
//   Collision-free: same h-row consecutive bases differ 27 (>=25);
//   h-boundary (32h+31 -> 32h+32) differs 27+4=31 (>=25).
//   Max index 255*27+28+24 = 6937 < 6944.
__device__ __forceinline__ int aidx_base(int child) {
    return child*27 + ((child>>5)<<2);
}

__global__ __launch_bounds__(256, 2) void attn_kernel(const float* __restrict__ q,   // [B][16384][32]
                                                      const float* __restrict__ kk,  // [B][4096][32]
                                                      const float* __restrict__ x,   // [B][256][64][64]
                                                      float* __restrict__ out)       // [B][256][128][128]
{
    __shared__ float sPool[4992];   // sK e-planar [32][12][13]; reused as sX [16][12][13]
    __shared__ float sA[6944];      // swizzled attn buffer, 256 children x 25
    int h0 = blockIdx.y * 8, w0 = blockIdx.x * 8;
    int b   = blockIdx.z >> 1;
    int ch0 = (blockIdx.z & 1) * 128;
    int tid = threadIdx.x;

    // ---- stage k halo (12x12 positions x 32 e), e-planar, zero-padded ----
    for (int i = tid; i < 1152; i += 256) {      // 1152 = 144 pos * 8 float4
        int posi = i >> 3, e4 = i & 7;
        int r = posi / 12, c = posi - 12*r;
        int gh = h0 + r - 2, gw = w0 + c - 2;
        float4 v = make_float4(0.f, 0.f, 0.f, 0.f);
        if (gh >= 0 && gh < 64 && gw >= 0 && gw < 64)
            v = *(const float4*)(kk + (((size_t)b*4096 + gh*64 + gw)*32 + e4*4));
        int base = r*13 + c;
        sPool[(e4*4+0)*156 + base] = v.x;
        sPool[(e4*4+1)*156 + base] = v.y;
        sPool[(e4*4+2)*156 + base] = v.z;
        sPool[(e4*4+3)*156 + base] = v.w;
    }

    int p = tid & 63, ci = tid >> 6;
    int w = p & 7, h = p >> 3;

    // ---- load q of the 4 children into registers ----
    float qv[4][32];
    int cb[4];
    #pragma unroll
    for (int u = 0; u < 2; ++u)
      #pragma unroll
      for (int v = 0; v < 2; ++v) {
        int uv = u*2 + v;
        int hh = 2*(h0+h) + u, ww = 2*(w0+w) + v;
        const float4* qp = (const float4*)(q + ((size_t)b*16384 + hh*128 + ww)*32);
        #pragma unroll
        for (int i4 = 0; i4 < 8; ++i4) {
            float4 t = qp[i4];
            qv[uv][i4*4+0]=t.x; qv[uv][i4*4+1]=t.y; qv[uv][i4*4+2]=t.z; qv[uv][i4*4+3]=t.w;
        }
        cb[uv] = aidx_base((2*h+u)*16 + 2*w+v);
      }
    __syncthreads();

    // ---- logits: wave ci handles ~6 of the 25 window positions ----
    int jlo = (ci == 0) ? 0 : (6*ci + 1);
    int jhi = 6*ci + 7; if (jhi > 25) jhi = 25;
    for (int j = jlo; j < jhi; ++j) {
        int dy = j / 5, dx = j - 5*dy;
        int base = (h+dy)*13 + (w+dx);
        float a0=0.f, a1=0.f, a2=0.f, a3=0.f;
        #pragma unroll
        for (int e = 0; e < 32; ++e) {
            float kv = sPool[e*156 + base];
            a0 = fmaf(qv[0][e], kv, a0);
            a1 = fmaf(qv[1][e], kv, a1);
            a2 = fmaf(qv[2][e], kv, a2);
            a3 = fmaf(qv[3][e], kv, a3);
        }
        sA[cb[0]+j] = a0; sA[cb[1]+j] = a1; sA[cb[2]+j] = a2; sA[cb[3]+j] = a3;
    }
    __syncthreads();

    // ---- softmax: thread = child pixel ----
    {
        int base = aidx_base(tid);
        float l[25], m = -1e30f;
        #pragma unroll
        for (int j = 0; j < 25; ++j) { l[j] = sA[base+j]; m = fmaxf(m, l[j]); }
        float s = 0.f;
        #pragma unroll
        for (int j = 0; j < 25; ++j) { l[j] = __expf(l[j] - m); s += l[j]; }
        float inv = 1.f / s;
        #pragma unroll
        for (int j = 0; j < 25; ++j) sA[base+j] = l[j] * inv;
    }
    __syncthreads();

    // ---- pull the 4 children's attn weights into registers ----
    float a[4][25];
    #pragma unroll
    for (int uv = 0; uv < 4; ++uv)
      #pragma unroll
      for (int j = 0; j < 25; ++j) a[uv][j] = sA[cb[uv]+j];

    // ---- gather: 8 chunks of 16 channels; wave ci owns 4 channels per chunk ----
    for (int c0 = 0; c0 < 128; c0 += 16) {
        __syncthreads();
        for (int t = tid; t < 2304; t += 256) {    // 16 ch * 144 pos
            int cc = t / 144, rc = t - 144*cc;
            int r = rc / 12, cl = rc - 12*r;
            int gh = h0 + r - 2, gw = w0 + cl - 2;
            float val = 0.f;
            if (gh >= 0 && gh < 64 && gw >= 0 && gw < 64)
                val = x[(((size_t)b*256 + ch0+c0+cc)*64 + gh)*64 + gw];
            sPool[cc*156 + r*13 + cl] = val;
        }
        __syncthreads();
        #pragma unroll
        for (int t = 0; t < 4; ++t) {
            int cc = ci*4 + t;
            int c  = ch0 + c0 + cc;
            float o0=0.f, o1=0.f, o2=0.f, o3=0.f;
            #pragma unroll
            for (int dy = 0; dy < 5; ++dy) {
                int rb = cc*156 + (h+dy)*13 + w;
                #pragma unroll
                for (int dx = 0; dx < 5; ++dx) {
                    float xv = sPool[rb + dx];
                    int j = dy*5 + dx;
                    o0 = fmaf(a[0][j], xv, o0);
                    o1 = fmaf(a[1][j], xv, o1);
                    o2 = fmaf(a[2][j], xv, o2);
                    o3 = fmaf(a[3][j], xv, o3);
                }
            }
            size_t ob = (((size_t)b*256 + c)*128 + 2*(h0+h))*128 + 2*(w0+w);
            *(float2*)(out + ob)       = make_float2(o0, o1);
            *(float2*)(out + ob + 128) = make_float2(o2, o3);
        }
    }
}

extern "C" void kernel_launch(void* const* d_in, const int* in_sizes, int n_in,
                              void* d_out, int out_size, void* d_ws, size_t ws_size,
                              hipStream_t stream) {
    const float* y   = (const float*)d_in[0];
    const float* x   = (const float*)d_in[1];
    const float* gyw = (const float*)d_in[2];
    const float* gyb = (const float*)d_in[3];
    const float* gxw = (const float*)d_in[4];
    const float* gxb = (const float*)d_in[5];
    const float* qw  = (const float*)d_in[6];
    const float* qb  = (const float*)d_in[7];
    const float* kw  = (const float*)d_in[8];
    const float* kb  = (const float*)d_in[9];
    float* out = (float*)d_out;
    float* ws  = (float*)d_ws;

    float* statsY = ws;             // 256 (sum, sumsq per b*32+g)
    float* statsX = ws + 256;       // 256
    float* WeffQ  = ws + 512;       // 32768
    float* beffQ  = ws + 33280;     // 128
    float* WeffK  = ws + 33408;     // 32768
    float* beffK  = ws + 66176;     // 128
    float* qbuf   = ws + 66304;     // 4*16384*32 = 2097152
    float* kbuf   = ws + 2163456;   // 4*4096*32  = 524288

    zero_kernel<<<2, 256, 0, stream>>>(ws, 512);
    stats_partial_kernel<<<1024, 256, 0, stream>>>(y, statsY, 3);
    stats_partial_kernel<<<256, 256, 0, stream>>>(x, statsX, 1);
    make_eff_kernel<<<128, 64, 0, stream>>>(qw, qb, gyw, gyb, statsY, 1.f/131072.f, WeffQ, beffQ);
    make_eff_kernel<<<128, 64, 0, stream>>>(kw, kb, gxw, gxb, statsX, 1.f/32768.f,  WeffK, beffK);
    proj_kernel<4><<<dim3(64, 4), 256, 0, stream>>>(y, WeffQ, beffQ, qbuf, 16384);
    proj_kernel<2><<<dim3(32, 4), 256, 0, stream>>>(x, WeffK, beffK, kbuf, 4096);
    attn_kernel<<<dim3(8, 8, 8), 256, 0, stream>>>(qbuf, kbuf, x, out);
}

// Round 4
// 255.594 us; speedup vs baseline: 1.4408x; 1.2097x over previous
//
#include <hip/hip_runtime.h>

#define EPSV 1e-5f

// ---------- fused stage-1 stats: blocks [0,1024) reduce y, [1024,1280) reduce x ----------
// part[bid] = (sum, sumsq) of 16384 contiguous floats. No atomics.
__global__ __launch_bounds__(256) void stats_kernel(const float* __restrict__ y,
                                                    const float* __restrict__ x,
                                                    float* __restrict__ part) {
    int bid = blockIdx.x;
    const float* src = (bid < 1024) ? (y + (size_t)bid * 16384)
                                    : (x + (size_t)(bid - 1024) * 16384);
    const float4* p = (const float4*)src;
    float s = 0.f, ss = 0.f;
    #pragma unroll 4
    for (int i = threadIdx.x; i < 4096; i += 256) {
        float4 v = p[i];
        s  += v.x + v.y + v.z + v.w;
        ss += v.x*v.x + v.y*v.y + v.z*v.z + v.w*v.w;
    }
    for (int off = 32; off > 0; off >>= 1) {
        s  += __shfl_down(s, off);
        ss += __shfl_down(ss, off);
    }
    __shared__ float red[8];
    int wid = threadIdx.x >> 6, lane = threadIdx.x & 63;
    if (lane == 0) { red[wid*2] = s; red[wid*2+1] = ss; }
    __syncthreads();
    if (threadIdx.x == 0) {
        part[bid*2+0] = red[0] + red[2] + red[4] + red[6];
        part[bid*2+1] = red[1] + red[3] + red[5] + red[7];
    }
}

// ---------- fused make_eff: blocks [0,128) build Q-side, [128,256) K-side ----------
__global__ __launch_bounds__(64) void make_eff_kernel(const float* __restrict__ qw, const float* __restrict__ qb,
                                                      const float* __restrict__ gyw, const float* __restrict__ gyb,
                                                      const float* __restrict__ kw, const float* __restrict__ kb,
                                                      const float* __restrict__ gxw, const float* __restrict__ gxb,
                                                      const float* __restrict__ part,
                                                      float* __restrict__ WeffQ, float* __restrict__ beffQ,
                                                      float* __restrict__ WeffK, float* __restrict__ beffK) {
    int id = blockIdx.x;
    int isK = id >> 7, b = (id >> 5) & 3, e = id & 31;
    const float* w     = isK ? kw  : qw;
    const float* bias  = isK ? kb  : qb;
    const float* gamma = isK ? gxw : gyw;
    const float* beta  = isK ? gxb : gyb;
    float inv_n = isK ? (1.f/32768.f) : (1.f/131072.f);
    float* W  = isK ? WeffK : WeffQ;
    float* be = isK ? beffK : beffQ;
    float partial = 0.f;
    for (int c = threadIdx.x; c < 256; c += 64) {
        int g = c >> 3, grp = b*32 + g;
        float s = 0.f, ss = 0.f;
        if (isK) {
            #pragma unroll
            for (int k2 = 0; k2 < 2; ++k2) {
                s  += part[(1024 + grp*2 + k2)*2 + 0];
                ss += part[(1024 + grp*2 + k2)*2 + 1];
            }
        } else {
            #pragma unroll
            for (int k2 = 0; k2 < 8; ++k2) {
                s  += part[(grp*8 + k2)*2 + 0];
                ss += part[(grp*8 + k2)*2 + 1];
            }
        }
        float mu = s * inv_n;
        float rs = rsqrtf(fmaf(-mu, mu, ss * inv_n) + EPSV);
        float wc = w[e*256 + c];
        float weff = wc * gamma[c] * rs;
        W[((size_t)b*256 + c)*32 + e] = weff;
        partial += wc * beta[c] - weff * mu;
    }
    for (int off = 32; off > 0; off >>= 1) partial += __shfl_down(partial, off);
    if (threadIdx.x == 0) be[b*32 + e] = partial + bias[e];
}

// ---------- fused 1x1 projection (y->q and x->k): dst[b][pix][e] ----------
// grid (128, 8): by<4 -> y batch by (128 px-blocks); by>=4 -> x batch by-4 (32 px-blocks).
// 256 thr = 64 px-groups (2 px) x 4 e-groups (8 e). Weights via wave-uniform s_load.
__global__ __launch_bounds__(256) void proj_kernel(const float* __restrict__ y, const float* __restrict__ x,
                                                   const float* __restrict__ WeffQ, const float* __restrict__ beffQ,
                                                   const float* __restrict__ WeffK, const float* __restrict__ beffK,
                                                   float* __restrict__ qbuf, float* __restrict__ kbuf) {
    int by = blockIdx.y;
    int isX = by >= 4;
    if (isX && blockIdx.x >= 32) return;
    int b = isX ? by - 4 : by;
    int npix = isX ? 4096 : 16384;
    const float* src   = isX ? x : y;
    const float* WeffT = isX ? WeffK : WeffQ;
    const float* beff  = isX ? beffK : beffQ;
    float* dst = isX ? kbuf : qbuf;

    int pix0 = blockIdx.x * 128 + (threadIdx.x & 63) * 2;
    int eg = __builtin_amdgcn_readfirstlane(threadIdx.x >> 6);
    const float* wp = WeffT + (size_t)b*256*32 + eg*8;
    float acc[2][8];
    #pragma unroll
    for (int j = 0; j < 8; ++j) {
        float bv = beff[b*32 + eg*8 + j];
        acc[0][j] = bv; acc[1][j] = bv;
    }
    const float* ysrc = src + (size_t)b*256*npix + pix0;
    #pragma unroll 8
    for (int c = 0; c < 256; ++c) {
        float2 t = *(const float2*)(ysrc + (size_t)c*npix);
        #pragma unroll
        for (int j = 0; j < 8; ++j) {
            float wj = wp[c*32 + j];
            acc[0][j] = fmaf(t.x, wj, acc[0][j]);
            acc[1][j] = fmaf(t.y, wj, acc[1][j]);
        }
    }
    float* dbase = dst + ((size_t)b*npix + pix0)*32 + eg*8;
    #pragma unroll
    for (int px = 0; px < 2; ++px) {
        float4 o0 = {acc[px][0], acc[px][1], acc[px][2], acc[px][3]};
        float4 o1 = {acc[px][4], acc[px][5], acc[px][6], acc[px][7]};
        *(float4*)(dbase + px*32 + 0) = o0;
        *(float4*)(dbase + px*32 + 4) = o1;
    }
}

// ---------- attention + gather ----------
// Block = 8x8 low-res tile, all 256 channels, grid (8,8,4).
// Logits/softmax: thread = child (tid = 32h+16u+2w+v) -> 4 same-parent children
//   share a wave and broadcast-read the same k address. q:32 regs, a[25] in regs.
// Transfer: sA[tid*27+j] (stride 27 -> collision-free, 2-way banks = free).
// Gather: thread = (parent p=tid&63, chgroup ci=tid>>6); sX [pos][16ch] stride 20
//   + 4-rotation swizzle; b128 reads = 4 channels/instr; a4[4][25]+acc[4][4] regs.
__global__ __launch_bounds__(256) void attn_kernel(const float* __restrict__ q,   // [B][16384][32]
                                                   const float* __restrict__ kk,  // [B][4096][32]
                                                   const float* __restrict__ x,   // [B][256][64][64]
                                                   float* __restrict__ out)       // [B][256][128][128]
{
    __shared__ __align__(16) float sPool[5184];  // k: [144 pos][36]; reused as x: [144 pos][20]
    __shared__ __align__(16) float sA[6912];     // 256 children * 27
    int h0 = blockIdx.y * 8, w0 = blockIdx.x * 8;
    int b = blockIdx.z;
    int tid = threadIdx.x;

    // ---- stage k halo: pos-major, stride 36, float4 ----
    for (int i = tid; i < 1152; i += 256) {     // 144 pos * 8 float4
        int pos = i >> 3, e4 = i & 7;
        int r = pos / 12, c = pos - 12*r;
        int gh = h0 + r - 2, gw = w0 + c - 2;
        float4 v = make_float4(0.f, 0.f, 0.f, 0.f);
        if (gh >= 0 && gh < 64 && gw >= 0 && gw < 64)
            v = *(const float4*)(kk + (((size_t)b*4096 + gh*64 + gw)*32 + e4*4));
        *(float4*)&sPool[pos*36 + e4*4] = v;
    }

    // ---- child decomposition ----
    int h = tid >> 5, u = (tid >> 4) & 1, w = (tid >> 1) & 7, v = tid & 1;

    // ---- load this child's q (32 regs) ----
    float qv[32];
    {
        int hh = 2*(h0 + h) + u, ww = 2*(w0 + w) + v;
        const float4* qp = (const float4*)(q + (((size_t)b*16384 + hh*128 + ww)*32));
        #pragma unroll
        for (int i4 = 0; i4 < 8; ++i4) {
            float4 t = qp[i4];
            qv[i4*4+0]=t.x; qv[i4*4+1]=t.y; qv[i4*4+2]=t.z; qv[i4*4+3]=t.w;
        }
    }
    __syncthreads();

    // ---- 25 logits per child, then in-register softmax ----
    float a[25];
    #pragma unroll
    for (int j = 0; j < 25; ++j) {
        int dy = j / 5, dx = j - 5*dy;
        const float4* kp = (const float4*)&sPool[((h+dy)*12 + (w+dx))*36];
        float acc = 0.f;
        #pragma unroll
        for (int e4 = 0; e4 < 8; ++e4) {
            float4 kv = kp[e4];
            acc = fmaf(qv[e4*4+0], kv.x, acc);
            acc = fmaf(qv[e4*4+1], kv.y, acc);
            acc = fmaf(qv[e4*4+2], kv.z, acc);
            acc = fmaf(qv[e4*4+3], kv.w, acc);
        }
        a[j] = acc;
    }
    {
        float m = -1e30f;
        #pragma unroll
        for (int j = 0; j < 25; ++j) m = fmaxf(m, a[j]);
        float s = 0.f;
        #pragma unroll
        for (int j = 0; j < 25; ++j) { a[j] = __expf(a[j] - m); s += a[j]; }
        float inv = 1.f / s;
        #pragma unroll
        for (int j = 0; j < 25; ++j) sA[tid*27 + j] = a[j] * inv;
    }
    __syncthreads();

    // ---- re-role: parent + channel group; pull 4 children's weights ----
    int p = tid & 63, ci = tid >> 6;
    int pw = p & 7, ph = p >> 3;
    float a4[4][25];
    #pragma unroll
    for (int uu = 0; uu < 2; ++uu)
      #pragma unroll
      for (int vv = 0; vv < 2; ++vv) {
        int cidx = 32*ph + 16*uu + 2*pw + vv;
        #pragma unroll
        for (int j = 0; j < 25; ++j) a4[uu*2+vv][j] = sA[cidx*27 + j];
      }

    // ---- gather: 16 chunks x 16 channels; wave ci owns channels ci*4..ci*4+3 ----
    int cc0 = ci * 4;
    for (int c0 = 0; c0 < 256; c0 += 16) {
        if (c0) __syncthreads();
        for (int t = tid; t < 2304; t += 256) {  // 16 ch * 144 pos, pos-inner (coalesced)
            int cc = t / 144, pos = t - 144*cc;
            int r = pos / 12, cl = pos - 12*r;
            int gh = h0 + r - 2, gw = w0 + cl - 2;
            float val = 0.f;
            if (gh >= 0 && gh < 64 && gw >= 0 && gw < 64)
                val = x[(((size_t)b*256 + c0 + cc)*64 + gh)*64 + gw];
            sPool[pos*20 + ((cc + 4*((pos>>3)&3)) & 15)] = val;
        }
        __syncthreads();

        float acc[4][4];
        #pragma unroll
        for (int uv = 0; uv < 4; ++uv)
            #pragma unroll
            for (int t = 0; t < 4; ++t) acc[uv][t] = 0.f;

        #pragma unroll
        for (int j = 0; j < 25; ++j) {
            int dy = j / 5, dx = j - 5*dy;
            int pos = (ph+dy)*12 + (pw+dx);
            float4 xv = *(const float4*)&sPool[pos*20 + ((cc0 + 4*((pos>>3)&3)) & 15)];
            #pragma unroll
            for (int uv = 0; uv < 4; ++uv) {
                float aw = a4[uv][j];
                acc[uv][0] = fmaf(aw, xv.x, acc[uv][0]);
                acc[uv][1] = fmaf(aw, xv.y, acc[uv][1]);
                acc[uv][2] = fmaf(aw, xv.z, acc[uv][2]);
                acc[uv][3] = fmaf(aw, xv.w, acc[uv][3]);
            }
        }
        #pragma unroll
        for (int t = 0; t < 4; ++t) {
            int c = c0 + cc0 + t;
            #pragma unroll
            for (int u2 = 0; u2 < 2; ++u2) {
                size_t ob = (((size_t)b*256 + c)*128 + 2*(h0+ph) + u2)*128 + 2*(w0+pw);
                *(float2*)(out + ob) = make_float2(acc[u2*2+0][t], acc[u2*2+1][t]);
            }
        }
    }
}

extern "C" void kernel_launch(void* const* d_in, const int* in_sizes, int n_in,
                              void* d_out, int out_size, void* d_ws, size_t ws_size,
                              hipStream_t stream) {
    const float* y   = (const float*)d_in[0];
    const float* x   = (const float*)d_in[1];
    const float* gyw = (const float*)d_in[2];
    const float* gyb = (const float*)d_in[3];
    const float* gxw = (const float*)d_in[4];
    const float* gxb = (const float*)d_in[5];
    const float* qw  = (const float*)d_in[6];
    const float* qb  = (const float*)d_in[7];
    const float* kw  = (const float*)d_in[8];
    const float* kb  = (const float*)d_in[9];
    float* out = (float*)d_out;
    float* ws  = (float*)d_ws;

    float* part  = ws;              // 2560
    float* WeffQ = ws + 2560;       // 32768
    float* beffQ = ws + 35328;      // 128
    float* WeffK = ws + 35456;      // 32768
    float* beffK = ws + 68224;      // 128
    float* qbuf  = ws + 68352;      // 4*16384*32 = 2097152
    float* kbuf  = ws + 2165504;    // 4*4096*32  = 524288

    stats_kernel<<<1280, 256, 0, stream>>>(y, x, part);
    make_eff_kernel<<<256, 64, 0, stream>>>(qw, qb, gyw, gyb, kw, kb, gxw, gxb,
                                            part, WeffQ, beffQ, WeffK, beffK);
    proj_kernel<<<dim3(128, 8), 256, 0, stream>>>(y, x, WeffQ, beffQ, WeffK, beffK, qbuf, kbuf);
    attn_kernel<<<dim3(8, 8, 4), 256, 0, stream>>>(qbuf, kbuf, x, out);
}

// Round 5
// 213.091 us; speedup vs baseline: 1.7281x; 1.1995x over previous
//
#include <hip/hip_runtime.h>

#define EPSV 1e-5f

// ---------- fused stage-1 stats: blocks [0,1024) reduce y, [1024,1280) reduce x ----------
__global__ __launch_bounds__(256) void stats_kernel(const float* __restrict__ y,
                                                    const float* __restrict__ x,
                                                    float* __restrict__ part) {
    int bid = blockIdx.x;
    const float* src = (bid < 1024) ? (y + (size_t)bid * 16384)
                                    : (x + (size_t)(bid - 1024) * 16384);
    const float4* p = (const float4*)src;
    float s = 0.f, ss = 0.f;
    #pragma unroll 8
    for (int i = threadIdx.x; i < 4096; i += 256) {
        float4 v = p[i];
        s  += v.x + v.y + v.z + v.w;
        ss += v.x*v.x + v.y*v.y + v.z*v.z + v.w*v.w;
    }
    for (int off = 32; off > 0; off >>= 1) {
        s  += __shfl_down(s, off);
        ss += __shfl_down(ss, off);
    }
    __shared__ float red[8];
    int wid = threadIdx.x >> 6, lane = threadIdx.x & 63;
    if (lane == 0) { red[wid*2] = s; red[wid*2+1] = ss; }
    __syncthreads();
    if (threadIdx.x == 0) {
        part[bid*2+0] = red[0] + red[2] + red[4] + red[6];
        part[bid*2+1] = red[1] + red[3] + red[5] + red[7];
    }
}

// ---------- fused make_eff: blocks [0,128) Q-side, [128,256) K-side ----------
__global__ __launch_bounds__(64) void make_eff_kernel(const float* __restrict__ qw, const float* __restrict__ qb,
                                                      const float* __restrict__ gyw, const float* __restrict__ gyb,
                                                      const float* __restrict__ kw, const float* __restrict__ kb,
                                                      const float* __restrict__ gxw, const float* __restrict__ gxb,
                                                      const float* __restrict__ part,
                                                      float* __restrict__ WeffQ, float* __restrict__ beffQ,
                                                      float* __restrict__ WeffK, float* __restrict__ beffK) {
    int id = blockIdx.x;
    int isK = id >> 7, b = (id >> 5) & 3, e = id & 31;
    const float* w     = isK ? kw  : qw;
    const float* bias  = isK ? kb  : qb;
    const float* gamma = isK ? gxw : gyw;
    const float* beta  = isK ? gxb : gyb;
    float inv_n = isK ? (1.f/32768.f) : (1.f/131072.f);
    float* W  = isK ? WeffK : WeffQ;
    float* be = isK ? beffK : beffQ;
    float partial = 0.f;
    for (int c = threadIdx.x; c < 256; c += 64) {
        int g = c >> 3, grp = b*32 + g;
        float s = 0.f, ss = 0.f;
        if (isK) {
            #pragma unroll
            for (int k2 = 0; k2 < 2; ++k2) {
                s  += part[(1024 + grp*2 + k2)*2 + 0];
                ss += part[(1024 + grp*2 + k2)*2 + 1];
            }
        } else {
            #pragma unroll
            for (int k2 = 0; k2 < 8; ++k2) {
                s  += part[(grp*8 + k2)*2 + 0];
                ss += part[(grp*8 + k2)*2 + 1];
            }
        }
        float mu = s * inv_n;
        float rs = rsqrtf(fmaf(-mu, mu, ss * inv_n) + EPSV);
        float wc = w[e*256 + c];
        float weff = wc * gamma[c] * rs;
        W[((size_t)b*256 + c)*32 + e] = weff;
        partial += wc * beta[c] - weff * mu;
    }
    for (int off = 32; off > 0; off >>= 1) partial += __shfl_down(partial, off);
    if (threadIdx.x == 0) be[b*32 + e] = partial + bias[e];
}

// ---------- fused 1x1 projection, flat 640-block grid ----------
// bid<512: y->q (b=bid>>7, 128 px-blocks); bid>=512: x->k (b=(bid-512)>>5, 32 px-blocks)
__global__ __launch_bounds__(256) void proj_kernel(const float* __restrict__ y, const float* __restrict__ x,
                                                   const float* __restrict__ WeffQ, const float* __restrict__ beffQ,
                                                   const float* __restrict__ WeffK, const float* __restrict__ beffK,
                                                   float* __restrict__ qbuf, float* __restrict__ kbuf) {
    int bid = blockIdx.x;
    int isX = bid >= 512;
    int lb = isX ? bid - 512 : bid;
    int b    = isX ? (lb >> 5) : (lb >> 7);
    int pxb  = isX ? (lb & 31) : (lb & 127);
    int npix = isX ? 4096 : 16384;
    const float* src   = isX ? x : y;
    const float* WeffT = isX ? WeffK : WeffQ;
    const float* beff  = isX ? beffK : beffQ;
    float* dst = isX ? kbuf : qbuf;

    int pix0 = pxb * 128 + (threadIdx.x & 63) * 2;
    int eg = __builtin_amdgcn_readfirstlane(threadIdx.x >> 6);
    const float* wp = WeffT + (size_t)b*256*32 + eg*8;
    float acc[2][8];
    #pragma unroll
    for (int j = 0; j < 8; ++j) {
        float bv = beff[b*32 + eg*8 + j];
        acc[0][j] = bv; acc[1][j] = bv;
    }
    const float* ysrc = src + (size_t)b*256*npix + pix0;
    #pragma unroll 8
    for (int c = 0; c < 256; ++c) {
        float2 t = *(const float2*)(ysrc + (size_t)c*npix);
        #pragma unroll
        for (int j = 0; j < 8; ++j) {
            float wj = wp[c*32 + j];
            acc[0][j] = fmaf(t.x, wj, acc[0][j]);
            acc[1][j] = fmaf(t.y, wj, acc[1][j]);
        }
    }
    float* dbase = dst + ((size_t)b*npix + pix0)*32 + eg*8;
    #pragma unroll
    for (int px = 0; px < 2; ++px) {
        float4 o0 = {acc[px][0], acc[px][1], acc[px][2], acc[px][3]};
        float4 o1 = {acc[px][4], acc[px][5], acc[px][6], acc[px][7]};
        *(float4*)(dbase + px*32 + 0) = o0;
        *(float4*)(dbase + px*32 + 4) = o1;
    }
}

// ---------- kernel A: attention weights ----------
// Block = 8x8 low-res tile, thread = child (tid = 32h+16u+2w+v).
// Writes attn maps [b][tile(64)][child(256)][25] via LDS bounce (coalesced).
__global__ __launch_bounds__(256) void attn_weights_kernel(const float* __restrict__ q,   // [B][16384][32]
                                                           const float* __restrict__ kk,  // [B][4096][32]
                                                           float* __restrict__ g_attn)    // [B][64][6400]
{
    __shared__ __align__(16) float sK[5184];   // [144 pos][36]
    __shared__ __align__(16) float sA[6400];   // [256 child][25]
    int h0 = blockIdx.y * 8, w0 = blockIdx.x * 8;
    int b = blockIdx.z;
    int tid = threadIdx.x;

    // stage k halo: pos-major, stride 36
    for (int i = tid; i < 1152; i += 256) {
        int pos = i >> 3, e4 = i & 7;
        int r = pos / 12, c = pos - 12*r;
        int gh = h0 + r - 2, gw = w0 + c - 2;
        float4 v = make_float4(0.f, 0.f, 0.f, 0.f);
        if (gh >= 0 && gh < 64 && gw >= 0 && gw < 64)
            v = *(const float4*)(kk + (((size_t)b*4096 + gh*64 + gw)*32 + e4*4));
        *(float4*)&sK[pos*36 + e4*4] = v;
    }

    int h = tid >> 5, u = (tid >> 4) & 1, w = (tid >> 1) & 7, v = tid & 1;

    float qv[32];
    {
        int hh = 2*(h0 + h) + u, ww = 2*(w0 + w) + v;
        const float4* qp = (const float4*)(q + (((size_t)b*16384 + hh*128 + ww)*32));
        #pragma unroll
        for (int i4 = 0; i4 < 8; ++i4) {
            float4 t = qp[i4];
            qv[i4*4+0]=t.x; qv[i4*4+1]=t.y; qv[i4*4+2]=t.z; qv[i4*4+3]=t.w;
        }
    }
    __syncthreads();

    float a[25];
    const float* kbase = &sK[(h*12 + w)*36];
    #pragma unroll
    for (int j = 0; j < 25; ++j) {
        int dy = j / 5, dx = j - 5*dy;
        const float4* kp = (const float4*)(kbase + (dy*12 + dx)*36);
        float acc = 0.f;
        #pragma unroll
        for (int e4 = 0; e4 < 8; ++e4) {
            float4 kv = kp[e4];
            acc = fmaf(qv[e4*4+0], kv.x, acc);
            acc = fmaf(qv[e4*4+1], kv.y, acc);
            acc = fmaf(qv[e4*4+2], kv.z, acc);
            acc = fmaf(qv[e4*4+3], kv.w, acc);
        }
        a[j] = acc;
    }
    {
        float m = -1e30f;
        #pragma unroll
        for (int j = 0; j < 25; ++j) m = fmaxf(m, a[j]);
        float s = 0.f;
        #pragma unroll
        for (int j = 0; j < 25; ++j) { a[j] = __expf(a[j] - m); s += a[j]; }
        float inv = 1.f / s;
        #pragma unroll
        for (int j = 0; j < 25; ++j) sA[tid*25 + j] = a[j] * inv;
    }
    __syncthreads();

    // coalesced copy out: 6400 floats = 1600 float4
    float4* gdst = (float4*)(g_attn + ((size_t)b*64 + blockIdx.y*8 + blockIdx.x)*6400);
    const float4* ssrc = (const float4*)sA;
    for (int i = tid; i < 1600; i += 256) gdst[i] = ssrc[i];
}

// ---------- kernel B: weighted gather ----------
// grid (8,8,16): bz = b*4 + slab(64 ch). Block = tile, thread = child.
// sX [144 pos][16 ch] stride 20 -> store bank = pos*5 mod 32 (conflict-free),
// b128 reads <=2-way. 4 same-parent children broadcast-read the same pos.
__global__ __launch_bounds__(256) void gather_kernel(const float* __restrict__ g_attn, // [B][64][6400]
                                                     const float* __restrict__ x,      // [B][256][64][64]
                                                     float* __restrict__ out)          // [B][256][128][128]
{
    __shared__ __align__(16) float sAttn[6400];
    __shared__ __align__(16) float sX[2880];   // 144*20
    int h0 = blockIdx.y * 8, w0 = blockIdx.x * 8;
    int b = blockIdx.z >> 2, slab = blockIdx.z & 3;
    int tid = threadIdx.x;

    // stage attn maps
    {
        const float4* gsrc = (const float4*)(g_attn + ((size_t)b*64 + blockIdx.y*8 + blockIdx.x)*6400);
        float4* sdst = (float4*)sAttn;
        for (int i = tid; i < 1600; i += 256) sdst[i] = gsrc[i];
    }
    __syncthreads();

    float a[25];
    #pragma unroll
    for (int j = 0; j < 25; ++j) a[j] = sAttn[tid*25 + j];

    int h = tid >> 5, u = (tid >> 4) & 1, w = (tid >> 1) & 7, v = tid & 1;
    int hh = 2*(h0 + h) + u, ww = 2*(w0 + w) + v;
    int vbase = (h*12 + w)*20;

    for (int c0 = 0; c0 < 64; c0 += 16) {
        if (c0) __syncthreads();
        // stage x chunk: 16 ch x 144 pos, pos-inner (coalesced global)
        for (int i = 0; i < 9; ++i) {
            int t = i*256 + tid;
            int cc = t / 144, pos = t - 144*cc;
            int r = pos / 12, cl = pos - 12*r;
            int gh = h0 + r - 2, gw = w0 + cl - 2;
            float val = 0.f;
            if (gh >= 0 && gh < 64 && gw >= 0 && gw < 64)
                val = x[(((size_t)b*256 + slab*64 + c0 + cc)*64 + gh)*64 + gw];
            sX[pos*20 + cc] = val;
        }
        __syncthreads();

        #pragma unroll
        for (int g = 0; g < 4; ++g) {
            float o0 = 0.f, o1 = 0.f, o2 = 0.f, o3 = 0.f;
            const float* xb = &sX[vbase + g*4];
            #pragma unroll
            for (int j = 0; j < 25; ++j) {
                int dy = j / 5, dx = j - 5*dy;
                float4 xv = *(const float4*)(xb + (dy*12 + dx)*20);
                float aw = a[j];
                o0 = fmaf(aw, xv.x, o0);
                o1 = fmaf(aw, xv.y, o1);
                o2 = fmaf(aw, xv.z, o2);
                o3 = fmaf(aw, xv.w, o3);
            }
            size_t ob = (((size_t)b*256 + slab*64 + c0 + g*4)*128 + hh)*128 + ww;
            out[ob]           = o0;
            out[ob + 16384]   = o1;
            out[ob + 32768]   = o2;
            out[ob + 49152]   = o3;
        }
    }
}

extern "C" void kernel_launch(void* const* d_in, const int* in_sizes, int n_in,
                              void* d_out, int out_size, void* d_ws, size_t ws_size,
                              hipStream_t stream) {
    const float* y   = (const float*)d_in[0];
    const float* x   = (const float*)d_in[1];
    const float* gyw = (const float*)d_in[2];
    const float* gyb = (const float*)d_in[3];
    const float* gxw = (const float*)d_in[4];
    const float* gxb = (const float*)d_in[5];
    const float* qw  = (const float*)d_in[6];
    const float* qb  = (const float*)d_in[7];
    const float* kw  = (const float*)d_in[8];
    const float* kb  = (const float*)d_in[9];
    float* out = (float*)d_out;
    float* ws  = (float*)d_ws;

    float* part   = ws;              // 2560
    float* WeffQ  = ws + 2560;       // 32768
    float* beffQ  = ws + 35328;      // 128
    float* WeffK  = ws + 35456;      // 32768
    float* beffK  = ws + 68224;      // 128
    float* qbuf   = ws + 68352;      // 4*16384*32 = 2097152
    float* kbuf   = ws + 2165504;    // 4*4096*32  = 524288
    float* attnbf = ws + 2689792;    // 4*64*6400  = 1638400  (total ~17.3 MB)

    stats_kernel<<<1280, 256, 0, stream>>>(y, x, part);
    make_eff_kernel<<<256, 64, 0, stream>>>(qw, qb, gyw, gyb, kw, kb, gxw, gxb,
                                            part, WeffQ, beffQ, WeffK, beffK);
    proj_kernel<<<640, 256, 0, stream>>>(y, x, WeffQ, beffQ, WeffK, beffK, qbuf, kbuf);
    attn_weights_kernel<<<dim3(8, 8, 4), 256, 0, stream>>>(qbuf, kbuf, attnbf);
    gather_kernel<<<dim3(8, 8, 16), 256, 0, stream>>>(attnbf, x, out);
}